// Round 1
// baseline (96.320 us; speedup 1.0000x reference)
//
#include <hip/hip_runtime.h>
#include <hip/hip_bf16.h>

typedef __attribute__((ext_vector_type(8))) short short8v;
typedef __attribute__((ext_vector_type(4))) float f32x4;

static constexpr int B_ = 4, S_ = 2048, E_ = 768, H_ = 12, D_ = 64;
static constexpr int NROWS = B_ * H_ * S_;       // 98304
static constexpr float LOG2E = 1.44269504088896340736f;
static constexpr float LN2 = 0.69314718055994530942f;

typedef __attribute__((address_space(3))) unsigned int lds_u32;
typedef const __attribute__((address_space(1))) unsigned int glb_u32;

__device__ __forceinline__ void gload16(const void* g, void* l) {
  __builtin_amdgcn_global_load_lds((glb_u32*)g, (lds_u32*)l, 16, 0, 0);
}

__device__ __forceinline__ unsigned short f2bf(float f) {
  union { float f; unsigned int u; } v; v.f = f;
  unsigned int u = v.u;
  unsigned int r = (u + 0x7fffu + ((u >> 16) & 1u)) >> 16;
  return (unsigned short)r;
}

__global__ __launch_bounds__(256) void cvt_x_kernel(const float4* __restrict__ x,
                                                    ushort4* __restrict__ xb, int n4) {
  int i = blockIdx.x * 256 + threadIdx.x;
  if (i >= n4) return;
  float4 v = x[i];
  ushort4 o;
  o.x = f2bf(v.x); o.y = f2bf(v.y); o.z = f2bf(v.z); o.w = f2bf(v.w);
  xb[i] = o;
}

// wb[1536][768]: rows 0..767 = beta[h]*log2e*W^Q; rows 768..1535 = W^K
__global__ __launch_bounds__(256) void cvt_w_kernel(const float4* __restrict__ wq,
                                                    const float4* __restrict__ wk,
                                                    const float* __restrict__ beta,
                                                    ushort4* __restrict__ wb, int n4) {
  int i = blockIdx.x * 256 + threadIdx.x;
  if (i < n4) {
    int row = i / (E_ / 4);
    float sc = beta[row >> 6] * LOG2E;
    float4 v = wq[i];
    ushort4 o;
    o.x = f2bf(v.x * sc); o.y = f2bf(v.y * sc); o.z = f2bf(v.z * sc); o.w = f2bf(v.w * sc);
    wb[i] = o;
  } else if (i < 2 * n4) {
    int j = i - n4;
    float4 v = wk[j];
    ushort4 o;
    o.x = f2bf(v.x); o.y = f2bf(v.y); o.z = f2bf(v.z); o.w = f2bf(v.w);
    wb[i] = o;
  }
}

// GEMM: C[8192,1536] = X[8192,768] * W[1536,768]^T, 128x128 tile, BK=32.
__global__ __launch_bounds__(256) void proj_kernel(const unsigned short* __restrict__ xb,
                                                   const unsigned short* __restrict__ wb,
                                                   unsigned short* __restrict__ Qb,
                                                   unsigned short* __restrict__ Kb) {
  __shared__ unsigned short lA[128 * 32];
  __shared__ unsigned short lB[128 * 32];
  const int mt = blockIdx.x, nt = blockIdx.y;
  const int t = threadIdx.x;
  const int wid = t >> 6, lane = t & 63, l15 = lane & 15, lhi = lane >> 4;
  const int wr = (wid >> 1) * 64, wc = (wid & 1) * 64;

  f32x4 acc[4][4] = {};

  const int row = t >> 2, ch = t & 3;
  const unsigned short* gA = xb + (size_t)(mt * 128 + row) * E_ + ch * 8;
  const unsigned short* gB = wb + (size_t)(nt * 128 + row) * E_ + ch * 8;

  for (int k0 = 0; k0 < E_; k0 += 32) {
    gload16(gA + k0, &lA[t * 8]);
    gload16(gA + (size_t)64 * E_ + k0, &lA[2048 + t * 8]);
    gload16(gB + k0, &lB[t * 8]);
    gload16(gB + (size_t)64 * E_ + k0, &lB[2048 + t * 8]);
    __syncthreads();
    short8v aF[4], bF[4];
#pragma unroll
    for (int m = 0; m < 4; ++m)
      aF[m] = *(const short8v*)&lA[(wr + m * 16 + l15) * 32 + lhi * 8];
#pragma unroll
    for (int n = 0; n < 4; ++n)
      bF[n] = *(const short8v*)&lB[(wc + n * 16 + l15) * 32 + lhi * 8];
#pragma unroll
    for (int m = 0; m < 4; ++m)
#pragma unroll
      for (int n = 0; n < 4; ++n)
        acc[m][n] = __builtin_amdgcn_mfma_f32_16x16x32_bf16(aF[m], bF[n], acc[m][n], 0, 0, 0);
    __syncthreads();
  }

  const int nbase = nt * 128 + wc;
  unsigned short* dst = (nbase < 768) ? Qb : Kb;
  const int nb = (nbase < 768) ? nbase : nbase - 768;
#pragma unroll
  for (int m = 0; m < 4; ++m)
#pragma unroll
    for (int n = 0; n < 4; ++n)
#pragma unroll
      for (int r = 0; r < 4; ++r) {
        int M = mt * 128 + wr + m * 16 + lhi * 4 + r;
        int col = nb + n * 16 + l15;
        int h = col >> 6, d = col & 63;
        int b = M >> 11, s = M & (S_ - 1);
        dst[((((size_t)b * H_ + h) * S_ + s) << 6) + d] = f2bf(acc[m][n][r]);
      }
}

// LSE row sums, LDS-free version. The per-(b,h) K panel (256 KB) is
// L2-resident (XCD map keeps all 32 blocks of one (b,h) on one XCD ->
// 3 MB working set). Each wave reads its own K fragments straight from
// L2 per 64x64 tile (8 x global_load_dwordx4 = 8 KB/tile/wave ->
// ~400 MB total @ ~13 TB/s, under the 34.5 TB/s L2 ceiling). No LDS,
// no barriers: 6144 independent waves (6/SIMD) hide L2 latency.
// Diagonal exclusion folded into the main loop (zero the diag element
// of the matching tile instead of recomputing a correction tile).
__global__ __launch_bounds__(256) void lse_kernel(const unsigned short* __restrict__ Qb,
                                                  const unsigned short* __restrict__ Kb,
                                                  float* __restrict__ rowsum) {
  const int L = blockIdx.x + 8 * (blockIdx.y + 12 * blockIdx.z);  // 0..1535
  const int xcd = L & 7, j = L >> 3;      // hw round-robins wgid%8 -> XCD
  const int split = j & 3;
  const int st = (j >> 2) & 7;
  const int g = xcd + 8 * (j >> 5);       // (b,h) group, 0..47
  const int h = g % H_, b = g / H_;

  const int tid = threadIdx.x;
  const int wid = tid >> 6, lane = tid & 63;
  const int l15 = lane & 15, lhi = lane >> 4;
  const size_t hb = ((size_t)b * H_ + h) * S_;
  const unsigned short* Qbase = Qb + hb * D_;
  const unsigned short* Kbase = Kb + hb * D_;
  const int s0 = st * 256 + wid * 64;     // 64 rows per wave
  const int tb = split * 512;             // 8 tiles of 64

  short8v q[4][2];
#pragma unroll
  for (int rb = 0; rb < 4; ++rb) {
    const unsigned short* qr = Qbase + (size_t)(s0 + rb * 16 + l15) * D_ + lhi * 8;
    q[rb][0] = *(const short8v*)qr;
    q[rb][1] = *(const short8v*)(qr + 32);
  }

  // tile index (within this split's 8 tiles) holding this wave's diagonal
  const int dtile = ((s0 >> 9) == split) ? ((s0 - tb) >> 6) : -1;

  f32x4 sp[4] = {};                       // sp[rb][r] row partial sums
  const unsigned short* kp = Kbase + ((size_t)tb << 6);

#pragma unroll 1
  for (int i = 0; i < 8; ++i) {
    short8v kf[4][2];
#pragma unroll
    for (int f = 0; f < 4; ++f) {
      const unsigned short* kr = kp + ((f * 16 + l15) << 6) + lhi * 8;
      kf[f][0] = *(const short8v*)kr;
      kf[f][1] = *(const short8v*)(kr + 32);
    }
    kp += 64 * D_;
    const bool isD = (i == dtile);

#pragma unroll
    for (int rb = 0; rb < 4; ++rb) {
      f32x4 acc[4] = {};
      __builtin_amdgcn_s_setprio(1);
#pragma unroll
      for (int f = 0; f < 4; ++f) {
        acc[f] = __builtin_amdgcn_mfma_f32_16x16x32_bf16(q[rb][0], kf[f][0], acc[f], 0, 0, 0);
        acc[f] = __builtin_amdgcn_mfma_f32_16x16x32_bf16(q[rb][1], kf[f][1], acc[f], 0, 0, 0);
      }
      __builtin_amdgcn_s_setprio(0);
#pragma unroll
      for (int f = 0; f < 4; ++f) {
        f32x4 e;
#pragma unroll
        for (int r = 0; r < 4; ++r) e[r] = __builtin_amdgcn_exp2f(acc[f][r]);
        if (f == rb && isD) {             // self-exclusion: zero diag element
#pragma unroll
          for (int r = 0; r < 4; ++r)
            if (l15 == lhi * 4 + r) e[r] = 0.f;
        }
        sp[rb] += e;                      // v_pk_add_f32 x2
      }
    }
  }

#pragma unroll
  for (int rb = 0; rb < 4; ++rb)
#pragma unroll
    for (int r = 0; r < 4; ++r) {
      float s = sp[rb][r];
#pragma unroll
      for (int off = 1; off < 16; off <<= 1) s += __shfl_xor(s, off, 64);
      if (l15 == 0)
        rowsum[(size_t)split * NROWS + hb + s0 + rb * 16 + lhi * 4 + r] = s;
    }
}

__global__ __launch_bounds__(256) void finish1_kernel(const float* __restrict__ rowsum,
                                                      const float* __restrict__ beta,
                                                      float* __restrict__ partial) {
  int row = blockIdx.x * 256 + threadIdx.x;
  float s = (rowsum[row] + rowsum[NROWS + row]) +
            (rowsum[2 * NROWS + row] + rowsum[3 * NROWS + row]);
  int h = (row >> 11) % H_;
  float c = __builtin_amdgcn_logf(s) * LN2 / beta[h];   // v_log_f32 = log2
#pragma unroll
  for (int off = 1; off < 64; off <<= 1) c += __shfl_xor(c, off, 64);
  __shared__ float wsum[4];
  int wid = threadIdx.x >> 6;
  if ((threadIdx.x & 63) == 0) wsum[wid] = c;
  __syncthreads();
  if (threadIdx.x == 0) partial[blockIdx.x] = wsum[0] + wsum[1] + wsum[2] + wsum[3];
}

__global__ __launch_bounds__(256) void finish2_kernel(const float* __restrict__ partial, int n,
                                                      float* __restrict__ out) {
  float s = 0.f;
  for (int i = threadIdx.x; i < n; i += 256) s += partial[i];
#pragma unroll
  for (int off = 1; off < 64; off <<= 1) s += __shfl_xor(s, off, 64);
  __shared__ float wsum[4];
  int wid = threadIdx.x >> 6;
  if ((threadIdx.x & 63) == 0) wsum[wid] = s;
  __syncthreads();
  if (threadIdx.x == 0) out[0] = -(wsum[0] + wsum[1] + wsum[2] + wsum[3]);
}

extern "C" void kernel_launch(void* const* d_in, const int* in_sizes, int n_in,
                              void* d_out, int out_size, void* d_ws, size_t ws_size,
                              hipStream_t stream) {
  const float* x    = (const float*)d_in[0];
  const float* wq   = (const float*)d_in[1];
  const float* wk   = (const float*)d_in[2];
  const float* beta = (const float*)d_in[3];

  char* ws = (char*)d_ws;
  const size_t xb_bytes = (size_t)B_ * S_ * E_ * 2;        // 12,582,912
  const size_t wb_bytes = (size_t)2 * H_ * D_ * E_ * 2;    //  2,359,296
  const size_t qk_bytes = (size_t)B_ * H_ * S_ * D_ * 2;   // 12,582,912
  const size_t rs_bytes = (size_t)4 * NROWS * 4;           //   1,572,864
  unsigned short* xb = (unsigned short*)ws;
  unsigned short* wb = (unsigned short*)(ws + xb_bytes);
  unsigned short* Qb = (unsigned short*)(ws + xb_bytes + wb_bytes);
  unsigned short* Kb = (unsigned short*)(ws + xb_bytes + wb_bytes + qk_bytes);
  float* rowsum      = (float*)(ws + xb_bytes + wb_bytes + 2 * qk_bytes);
  float* partial     = (float*)(ws + xb_bytes + wb_bytes + 2 * qk_bytes + rs_bytes);

  int nx4 = (B_ * S_ * E_) / 4;
  cvt_x_kernel<<<(nx4 + 255) / 256, 256, 0, stream>>>((const float4*)x, (ushort4*)xb, nx4);

  int nw4 = (H_ * D_ * E_) / 4;
  cvt_w_kernel<<<(2 * nw4 + 255) / 256, 256, 0, stream>>>((const float4*)wq, (const float4*)wk,
                                                          beta, (ushort4*)wb, nw4);

  dim3 pgrid((B_ * S_) / 128, (2 * H_ * D_) / 128);   // 64 x 12
  proj_kernel<<<pgrid, 256, 0, stream>>>(xb, wb, Qb, Kb);

  dim3 lgrid(S_ / 256, H_, B_ * 4);                    // 8 x 12 x 16 = 1536 blocks
  lse_kernel<<<lgrid, 256, 0, stream>>>(Qb, Kb, rowsum);

  finish1_kernel<<<NROWS / 256, 256, 0, stream>>>(rowsum, beta, partial);
  finish2_kernel<<<1, 256, 0, stream>>>(partial, NROWS / 256, (float*)d_out);
}